// Round 3
// baseline (305.917 us; speedup 1.0000x reference)
//
#include <hip/hip_runtime.h>

#define ITERS 8  // m's per block; grid = M/ITERS

// Async global->LDS, 16B per lane. Hardware: dest = wave-uniform base + lane*16.
__device__ __forceinline__ void gload_lds16(const float* g, float* l) {
  __builtin_amdgcn_global_load_lds(
      (const __attribute__((address_space(1))) unsigned int*)g,
      (__attribute__((address_space(3))) unsigned int*)l, 16, 0, 0);
}

__global__ __launch_bounds__(256, 2) void fine_matching_kernel(
    const float* __restrict__ feat0, const float* __restrict__ feat1,
    float* __restrict__ out, int M)
{
  const int t    = threadIdx.x;
  const int lane = t & 63;
  const int wave = t >> 6;

  // Linear layouts (required by global_load_lds). Content is source-side
  // XOR-swizzled: slot (p, quad q) holds global channel-quad q ^ ((p>>2)&7).
  __shared__ __align__(16) float sA[2][4096];   // cls_f0, 2 buffers
  __shared__ __align__(16) float sB[2][4096];   // cls_f1 inner, 2 buffers
  __shared__ __align__(16) float colps[4][64];  // per-wave col-sum partials
  __shared__ float redv[4];
  __shared__ int   redi[4];

  const int st = t & 15, lt = t >> 4;
  const int s4 = st << 2, l4 = lt << 2;
  const int axs = (lt & 7) << 2;   // read-side XOR for A rows l4..l4+3 (e(p)=lt&7)
  const int bxs = (st & 7) << 2;   // read-side XOR for B rows s4..s4+3 (e(p)=st&7)

  const int m0 = blockIdx.x * ITERS;

  auto stage = [&](int buf, int m) {
    const float* f0m = feat0 + (size_t)m * 8192;   // 64*128
    const float* f1m = feat1 + (size_t)m * 12800;  // 100*128
    const int pr = lane >> 4;           // row within 4-row group
    const int cq = (lane & 15) << 2;    // channel base 0..60
#pragma unroll
    for (int k = 0; k < 4; ++k) {
      int p = wave * 16 + k * 4 + pr;               // position 0..63
      int e = ((p >> 2) & 7) << 2;                  // source-side swizzle
      gload_lds16(f0m + p * 128 + (cq ^ e), &sA[buf][(wave * 16 + k * 4) * 64]);
      int row = (p >> 3) + 1, col = (p & 7) + 1;    // inner mask of 10x10
      gload_lds16(f1m + (row * 10 + col) * 128 + (cq ^ e),
                  &sB[buf][(wave * 16 + k * 4) * 64]);
    }
  };

  // ---- prologue: stage first m ----
  stage(0, m0);

  int cur = 0;
  for (int it = 0; it < ITERS; ++it) {
    const int m = m0 + it;
    const float* f0m = feat0 + (size_t)m * 8192;
    const float* f1m = feat1 + (size_t)m * 12800;

    // top barrier: my staged loads for buf[cur] done; all waves finished prev compute
    asm volatile("s_waitcnt vmcnt(0) lgkmcnt(0)" ::: "memory");
    __builtin_amdgcn_s_barrier();
    asm volatile("" ::: "memory");

    // issue prefetch for next m (stays in flight across the barriers below)
    if (it + 1 < ITERS) stage(cur ^ 1, m + 1);

    // ---- phase B: sim 4x4 register tile, K=64 ----
    const float* A = sA[cur];
    const float* B = sB[cur];
    float acc[4][4] = {};
#pragma unroll 4
    for (int c = 0; c < 64; c += 4) {
      float4 a[4], b[4];
#pragma unroll
      for (int i = 0; i < 4; ++i) a[i] = *(const float4*)(&A[(l4 + i) * 64 + (c ^ axs)]);
#pragma unroll
      for (int j = 0; j < 4; ++j) b[j] = *(const float4*)(&B[(s4 + j) * 64 + (c ^ bxs)]);
#pragma unroll
      for (int i = 0; i < 4; ++i)
#pragma unroll
        for (int j = 0; j < 4; ++j)
          acc[i][j] += a[i].x * b[j].x + a[i].y * b[j].y + a[i].z * b[j].z + a[i].w * b[j].w;
    }

    // ---- softmax stats, unshifted (|sim|<=~1, exp well-conditioned) ----
    // e = exp(sim/64); heatmap = e^2 * rinv * cinv
    float rinv[4];
#pragma unroll
    for (int i = 0; i < 4; ++i) {
      float rs = 0.0f;
#pragma unroll
      for (int j = 0; j < 4; ++j) { acc[i][j] = __expf(acc[i][j] * 0.015625f); rs += acc[i][j]; }
#pragma unroll
      for (int off = 1; off <= 8; off <<= 1) rs += __shfl_xor(rs, off);
      rinv[i] = 1.0f / rs;
    }
    {
      float cps[4];
#pragma unroll
      for (int j = 0; j < 4; ++j) {
        float cs = acc[0][j] + acc[1][j] + acc[2][j] + acc[3][j];
        cs += __shfl_xor(cs, 16);
        cs += __shfl_xor(cs, 32);
        cps[j] = cs;
      }
      if (lane < 16) *(float4*)(&colps[wave][s4]) = make_float4(cps[0], cps[1], cps[2], cps[3]);
    }
    // LDS-only barrier (no vmcnt drain -> prefetch stays in flight)
    asm volatile("s_waitcnt lgkmcnt(0)" ::: "memory");
    __builtin_amdgcn_s_barrier();
    asm volatile("" ::: "memory");

    float cinv[4];
    {
      float4 q0 = *(const float4*)(&colps[0][s4]);
      float4 q1 = *(const float4*)(&colps[1][s4]);
      float4 q2 = *(const float4*)(&colps[2][s4]);
      float4 q3 = *(const float4*)(&colps[3][s4]);
      cinv[0] = 1.0f / (q0.x + q1.x + q2.x + q3.x);
      cinv[1] = 1.0f / (q0.y + q1.y + q2.y + q3.y);
      cinv[2] = 1.0f / (q0.z + q1.z + q2.z + q3.z);
      cinv[3] = 1.0f / (q0.w + q1.w + q2.w + q3.w);
    }

    // ---- heatmap write + argmax ----
    float best = -1.0f; int bidx = 0;
    float* outh = out + (size_t)m * 4096;
#pragma unroll
    for (int i = 0; i < 4; ++i) {
      float ri = rinv[i];
      float4 h;
      h.x = acc[i][0] * acc[i][0] * ri * cinv[0];
      h.y = acc[i][1] * acc[i][1] * ri * cinv[1];
      h.z = acc[i][2] * acc[i][2] * ri * cinv[2];
      h.w = acc[i][3] * acc[i][3] * ri * cinv[3];
      int base = (l4 + i) * 64 + s4;
      *(float4*)(outh + base) = h;
      if (h.x > best) { best = h.x; bidx = base; }
      if (h.y > best) { best = h.y; bidx = base + 1; }
      if (h.z > best) { best = h.z; bidx = base + 2; }
      if (h.w > best) { best = h.w; bidx = base + 3; }
    }
#pragma unroll
    for (int off = 32; off; off >>= 1) {
      float ov = __shfl_xor(best, off);
      int   oi = __shfl_xor(bidx, off);
      if (ov > best || (ov == best && oi < bidx)) { best = ov; bidx = oi; }
    }
    if (lane == 0) { redv[wave] = best; redi[wave] = bidx; }
    asm volatile("s_waitcnt lgkmcnt(0)" ::: "memory");
    __builtin_amdgcn_s_barrier();
    asm volatile("" ::: "memory");

    // all threads reduce the 4 wave results redundantly (no extra barrier)
    float fbv = redv[0]; int fbi = redi[0];
#pragma unroll
    for (int w = 1; w < 4; ++w) {
      float ov = redv[w]; int oi = redi[w];
      if (ov > fbv || (ov == fbv && oi < fbi)) { fbv = ov; fbi = oi; }
    }
    const int i0 = fbi >> 6, i1 = fbi & 63;

    if (t == 0) {
      float* o = out + (size_t)M * 4096;
      o[m]         = (float)i0;                       // idxes0
      o[M + m]     = (float)i1;                       // idxes1
      o[2 * M + 2 * m + 0] = (float)(i0 & 7) - 3.5f;  // biases0.x
      o[2 * M + 2 * m + 1] = (float)(i0 >> 3) - 3.5f; // biases0.y
      o[4 * M + 2 * m + 0] = (float)(i1 & 7) - 3.5f;  // biases1.x
      o[4 * M + 2 * m + 1] = (float)(i1 >> 3) - 3.5f; // biases1.y
    }

    // ---- phase C: reg refinement (wave 0; lane = channel) ----
    if (wave == 0) {
      float rf0 = f0m[i0 * 128 + 64 + lane];
      int r0 = i1 >> 3, c0 = i1 & 7;
      float p[9];
#pragma unroll
      for (int a = 0; a < 3; ++a)
#pragma unroll
        for (int b = 0; b < 3; ++b)
          p[a * 3 + b] = f1m[((r0 + a) * 10 + (c0 + b)) * 128 + 64 + lane] * rf0;
#pragma unroll
      for (int r = 0; r < 9; ++r)
#pragma unroll
        for (int off = 32; off; off >>= 1)
          p[r] += __shfl_xor(p[r], off);
      if (lane == 0) {
        float mx = p[0];
#pragma unroll
        for (int r = 1; r < 9; ++r) mx = fmaxf(mx, p[r]);
        float e[9], ssum = 0.0f;
#pragma unroll
        for (int r = 0; r < 9; ++r) { e[r] = __expf((p[r] - mx) * 0.125f); ssum += e[r]; }
        float inv = 1.0f / ssum, bx = 0.0f, by = 0.0f;
#pragma unroll
        for (int r = 0; r < 9; ++r) {
          float w = e[r] * inv;
          bx += w * (float)((r % 3) - 1);
          by += w * (float)((r / 3) - 1);
        }
        float* o = out + (size_t)M * 4096;
        o[6 * M + 2 * m + 0] = bx;
        o[6 * M + 2 * m + 1] = by;
      }
    }

    cur ^= 1;
  }
}

extern "C" void kernel_launch(void* const* d_in, const int* in_sizes, int n_in,
                              void* d_out, int out_size, void* d_ws, size_t ws_size,
                              hipStream_t stream) {
  const float* f0 = (const float*)d_in[0];
  const float* f1 = (const float*)d_in[1];
  float* out = (float*)d_out;
  int M = in_sizes[0] / 8192;  // 64*128 per row
  fine_matching_kernel<<<dim3(M / ITERS), dim3(256), 0, stream>>>(f0, f1, out, M);
}